// Round 1
// baseline (82.125 us; speedup 1.0000x reference)
//
#include <hip/hip_runtime.h>

// LIF layer: input (T=256, B=32, N=4096) fp32.
// Recurrence over T; B*N columns independent.
// Outputs concatenated: spikes[T][B*N] (0/1 f32), voltages[T][B*N] (post-reset).

#define T_STEPS 256
#define BN      (32 * 4096)      // 131072
#define COLS    (BN / 4)         // 32768 float4 columns

__global__ __launch_bounds__(128) void lif_kernel(
    const float4* __restrict__ in,
    float* __restrict__ out,
    const float* __restrict__ decay_p,
    const float* __restrict__ vth_p,
    const float* __restrict__ vreset_p)
{
    const int col = blockIdx.x * 128 + threadIdx.x;   // 0..COLS-1
    if (col >= COLS) return;

    const float decay   = *decay_p;
    const float v_th    = *vth_p;
    const float v_reset = *vreset_p;

    float4* __restrict__ spikes = (float4*)out;                            // [T][BN/4]
    float4* __restrict__ volts  = (float4*)(out + (size_t)T_STEPS * BN);   // [T][BN/4]

    const float4* ip = in     + col;
    float4*       sp = spikes + col;
    float4*       vp = volts  + col;

    float vx = 0.f, vy = 0.f, vz = 0.f, vw = 0.f;

    // Independent per-t load addresses + __restrict__ let the compiler hoist
    // loads across stores within the unrolled window (latency hiding).
    #pragma unroll 8
    for (int t = 0; t < T_STEPS; ++t) {
        float4 I = ip[(size_t)t * COLS];
        float4 s, v;
        float n;
        // decay*V + I with SEPARATE mul/add roundings (match numpy; no FMA).
        n = __fadd_rn(__fmul_rn(decay, vx), I.x);
        s.x = (n >= v_th) ? 1.f : 0.f;  vx = (n >= v_th) ? v_reset : n;  v.x = vx;

        n = __fadd_rn(__fmul_rn(decay, vy), I.y);
        s.y = (n >= v_th) ? 1.f : 0.f;  vy = (n >= v_th) ? v_reset : n;  v.y = vy;

        n = __fadd_rn(__fmul_rn(decay, vz), I.z);
        s.z = (n >= v_th) ? 1.f : 0.f;  vz = (n >= v_th) ? v_reset : n;  v.z = vz;

        n = __fadd_rn(__fmul_rn(decay, vw), I.w);
        s.w = (n >= v_th) ? 1.f : 0.f;  vw = (n >= v_th) ? v_reset : n;  v.w = vw;

        sp[(size_t)t * COLS] = s;
        vp[(size_t)t * COLS] = v;
    }
}

extern "C" void kernel_launch(void* const* d_in, const int* in_sizes, int n_in,
                              void* d_out, int out_size, void* d_ws, size_t ws_size,
                              hipStream_t stream) {
    const float4* in      = (const float4*)d_in[0];
    const float*  decay_p = (const float*)d_in[1];
    const float*  vth_p   = (const float*)d_in[2];
    const float*  vrst_p  = (const float*)d_in[3];
    float*        out     = (float*)d_out;

    dim3 grid(COLS / 128);   // 256 blocks
    dim3 block(128);
    hipLaunchKernelGGL(lif_kernel, grid, block, 0, stream,
                       in, out, decay_p, vth_p, vrst_p);
}